// Round 1
// baseline (1036.066 us; speedup 1.0000x reference)
//
#include <hip/hip_runtime.h>
#include <math.h>

#define NNODES 100000
#define NFEAT  256
#define HID    128
#define NCLS   40
#define KHOP   4
#define RWSAMP 10
#define KP1    5

// ---------------------------------------------------------------------------
// GEMM: C[M,128] = A[M,K] @ W[K,128] + bias   (fp32, K in {256,128}, K%32==0)
// BM=64, BN=128, BK=32; 256 threads; micro-tile TM=4 x TN=8 per thread.
// A staged transposed in LDS (pad +1) so compute reads are conflict-light.
// ---------------------------------------------------------------------------
__global__ __launch_bounds__(256) void gemm128(
    const float* __restrict__ A, const float* __restrict__ W,
    const float* __restrict__ bias, float* __restrict__ C,
    int M, int K)
{
    __shared__ float AsT[32][65];    // [kk][m], padded stride 65
    __shared__ float Bs[32][128];    // [kk][n]

    const int tid = threadIdx.x;
    const int tx  = tid & 15;        // n0 = tx*8
    const int ty  = tid >> 4;        // m0 = ty*4
    const int blockRow = blockIdx.x * 64;

    float acc[4][8];
#pragma unroll
    for (int i = 0; i < 4; ++i)
#pragma unroll
        for (int j = 0; j < 8; ++j) acc[i][j] = 0.0f;

    for (int k0 = 0; k0 < K; k0 += 32) {
        // --- stage A tile: 64 rows x 32 k -> 512 float4, 2 per thread ---
#pragma unroll
        for (int l = 0; l < 2; ++l) {
            int f   = tid + l * 256;
            int row = f >> 3;            // 8 float4 per row
            int kc  = (f & 7) << 2;
            int gr  = blockRow + row;
            gr = (gr < M) ? gr : (M - 1);   // clamp; OOB rows never stored
            const float4 v = *(const float4*)(A + (size_t)gr * K + k0 + kc);
            AsT[kc + 0][row] = v.x;
            AsT[kc + 1][row] = v.y;
            AsT[kc + 2][row] = v.z;
            AsT[kc + 3][row] = v.w;
        }
        // --- stage B tile: 32 x 128 -> 1024 float4, 4 per thread ---
#pragma unroll
        for (int l = 0; l < 4; ++l) {
            int f   = tid + l * 256;
            int row = f >> 5;            // 32 float4 per row
            int c4  = (f & 31) << 2;
            *(float4*)(&Bs[row][c4]) =
                *(const float4*)(W + (size_t)(k0 + row) * 128 + c4);
        }
        __syncthreads();

#pragma unroll 8
        for (int kk = 0; kk < 32; ++kk) {
            float a0 = AsT[kk][ty * 4 + 0];
            float a1 = AsT[kk][ty * 4 + 1];
            float a2 = AsT[kk][ty * 4 + 2];
            float a3 = AsT[kk][ty * 4 + 3];
            float4 bv0 = *(const float4*)(&Bs[kk][tx * 8]);
            float4 bv1 = *(const float4*)(&Bs[kk][tx * 8 + 4]);
            float bj[8] = {bv0.x, bv0.y, bv0.z, bv0.w,
                           bv1.x, bv1.y, bv1.z, bv1.w};
            float aa[4] = {a0, a1, a2, a3};
#pragma unroll
            for (int i = 0; i < 4; ++i)
#pragma unroll
                for (int j = 0; j < 8; ++j)
                    acc[i][j] = fmaf(aa[i], bj[j], acc[i][j]);
        }
        __syncthreads();
    }

#pragma unroll
    for (int i = 0; i < 4; ++i) {
        int gr = blockRow + ty * 4 + i;
        if (gr < M) {
#pragma unroll
            for (int j = 0; j < 8; ++j)
                C[(size_t)gr * 128 + tx * 8 + j] = acc[i][j] + bias[tx * 8 + j];
        }
    }
}

// ---------------------------------------------------------------------------
// Aggregation + ReLU: one block (128 threads) per node, one feature per thread.
// agg = att0*h[n] + sum_k att[k+1]/RWS * sum_s w(n,e)*h[e];  h' = relu(agg)
// ---------------------------------------------------------------------------
__global__ __launch_bounds__(128) void agg_relu(
    const float* __restrict__ hin, float* __restrict__ hout,
    const int* __restrict__ ends,       // [KHOP][NNODES*RWSAMP] this layer
    const float* __restrict__ degree,
    const float* __restrict__ att)      // [KP1] this layer
{
    __shared__ int   sidx[KHOP * RWSAMP];
    __shared__ float sw[KHOP * RWSAMP];

    const int n = blockIdx.x;
    const int t = threadIdx.x;

    if (t < KHOP * RWSAMP) {
        const int k = t / RWSAMP;
        const int s = t - k * RWSAMP;
        const int e = ends[(size_t)k * (NNODES * RWSAMP) + (size_t)n * RWSAMP + s];
        sidx[t] = e;
        sw[t] = att[k + 1] * (1.0f / RWSAMP) * sqrtf(degree[n]) * rsqrtf(degree[e]);
    }
    __syncthreads();

    float acc = att[0] * hin[(size_t)n * HID + t];
#pragma unroll 8
    for (int j = 0; j < KHOP * RWSAMP; ++j)
        acc = fmaf(sw[j], hin[(size_t)sidx[j] * HID + t], acc);

    hout[(size_t)n * HID + t] = fmaxf(acc, 0.0f);
}

// ---------------------------------------------------------------------------
// Head: logits = h @ W2 + b2 ; out = log_softmax(logits). One wave per node,
// lane c (<40) owns class c; shuffle-reduce max and sum over the wave.
// ---------------------------------------------------------------------------
__global__ __launch_bounds__(256) void head_logsoftmax(
    const float* __restrict__ h, const float* __restrict__ W2,
    const float* __restrict__ b2, float* __restrict__ out)
{
    const int lane = threadIdx.x & 63;
    const int wv   = threadIdx.x >> 6;
    const int n    = blockIdx.x * 4 + wv;
    if (n >= NNODES) return;

    float logit = -INFINITY;
    if (lane < NCLS) {
        float acc = b2[lane];
        const float* hr = h + (size_t)n * HID;
#pragma unroll 8
        for (int j = 0; j < HID; ++j)
            acc = fmaf(hr[j], W2[j * NCLS + lane], acc);
        logit = acc;
    }

    float m = logit;
#pragma unroll
    for (int off = 32; off > 0; off >>= 1)
        m = fmaxf(m, __shfl_xor(m, off, 64));

    float e = (lane < NCLS) ? __expf(logit - m) : 0.0f;
    float s = e;
#pragma unroll
    for (int off = 32; off > 0; off >>= 1)
        s += __shfl_xor(s, off, 64);

    if (lane < NCLS)
        out[(size_t)n * NCLS + lane] = (logit - m) - __logf(s);
}

extern "C" void kernel_launch(void* const* d_in, const int* in_sizes, int n_in,
                              void* d_out, int out_size, void* d_ws, size_t ws_size,
                              hipStream_t stream)
{
    const float* x      = (const float*)d_in[0];
    const float* degree = (const float*)d_in[1];
    const int*   ends   = (const int*)  d_in[2];
    const float* att    = (const float*)d_in[3];
    const float* W0     = (const float*)d_in[4];
    const float* b0     = (const float*)d_in[5];
    const float* W1     = (const float*)d_in[6];
    const float* b1     = (const float*)d_in[7];
    const float* W2     = (const float*)d_in[8];
    const float* b2     = (const float*)d_in[9];
    float* out = (float*)d_out;

    float* buf0 = (float*)d_ws;                       // [NNODES, HID]
    float* buf1 = buf0 + (size_t)NNODES * HID;        // [NNODES, HID]

    const dim3 gGemm((NNODES + 63) / 64);

    // layer 0
    gemm128<<<gGemm, 256, 0, stream>>>(x, W0, b0, buf0, NNODES, NFEAT);
    agg_relu<<<NNODES, 128, 0, stream>>>(buf0, buf1, ends, degree, att);
    // layer 1
    gemm128<<<gGemm, 256, 0, stream>>>(buf1, W1, b1, buf0, NNODES, HID);
    agg_relu<<<NNODES, 128, 0, stream>>>(
        buf0, buf1, ends + (size_t)KHOP * NNODES * RWSAMP, degree, att + KP1);
    // head
    head_logsoftmax<<<NNODES / 4, 256, 0, stream>>>(buf1, W2, b2, out);
}

// Round 2
// 589.122 us; speedup vs baseline: 1.7587x; 1.7587x over previous
//
#include <hip/hip_runtime.h>
#include <math.h>

#define NNODES 100000
#define NFEAT  256
#define HID    128
#define NCLS   40
#define KHOP   4
#define RWSAMP 10
#define KP1    5

typedef __bf16 bf16;
typedef __attribute__((ext_vector_type(8)))  __bf16 bf16x8;
typedef __attribute__((ext_vector_type(16))) float  f32x16;

#define LDK 72   // LDS k-stride in bf16 elems: 144 B, 16B-aligned, spreads banks

// ---------------------------------------------------------------------------
// Prep: Wt0[n][k] = bf16(W0[k][n]) (128x256), Wt1[n][k] = bf16(W1[k][n]) (128x128)
// ---------------------------------------------------------------------------
__global__ __launch_bounds__(256) void prep_w(
    const float* __restrict__ W0, const float* __restrict__ W1,
    bf16* __restrict__ Wt0, bf16* __restrict__ Wt1)
{
    int tid = blockIdx.x * 256 + threadIdx.x;
    if (tid < 128 * 256) {
        int n = tid >> 8, k = tid & 255;
        Wt0[tid] = (bf16)W0[k * 128 + n];
    } else if (tid < 128 * 256 + 128 * 128) {
        int i = tid - 128 * 256;
        int n = i >> 7, k = i & 127;
        Wt1[i] = (bf16)W1[k * 128 + n];
    }
}

// ---------------------------------------------------------------------------
// GEMM via MFMA 32x32x16 bf16: C_bf16[M,128] = bf16(A @ W + bias)
// A fp32 (layer0, converted during staging) or bf16 (layer1).
// Block 256 thr = 4 waves; tile M=128 (32 rows/wave), N=128 (4 col-tiles/wave),
// K-step 64. Wt is pre-transposed [128][K] so B-frags are contiguous.
// ---------------------------------------------------------------------------
template<bool A_IS_BF16>
__global__ __launch_bounds__(256) void gemm_mfma(
    const void* __restrict__ Av, const bf16* __restrict__ Wt,
    const float* __restrict__ bias, bf16* __restrict__ C,
    int M, int K)
{
    __shared__ bf16 As[128 * LDK];   // [m][k]
    __shared__ bf16 Bs[128 * LDK];   // [n][k]  (transposed W tile)

    const int tid  = threadIdx.x;
    const int wv   = tid >> 6;
    const int lane = tid & 63;
    const int l31  = lane & 31;
    const int lhi  = lane >> 5;
    const int blockRow = blockIdx.x * 128;

    f32x16 acc[4];
#pragma unroll
    for (int t = 0; t < 4; ++t)
#pragma unroll
        for (int r = 0; r < 16; ++r) acc[t][r] = 0.0f;

    for (int k0 = 0; k0 < K; k0 += 64) {
        if (A_IS_BF16) {
            // 128 rows x 64 bf16 = 1024 x 16B chunks; 4 per thread
#pragma unroll
            for (int l = 0; l < 4; ++l) {
                int f = tid + l * 256;
                int row = f >> 3;
                int c = (f & 7) * 8;
                int gr = min(blockRow + row, M - 1);
                uint4 v = *(const uint4*)((const bf16*)Av + (size_t)gr * K + k0 + c);
                *(uint4*)&As[row * LDK + c] = v;
            }
        } else {
            // 128 rows x 64 fp32 = 2048 float4; 8 per thread; convert to bf16
#pragma unroll
            for (int l = 0; l < 8; ++l) {
                int f = tid + l * 256;
                int row = f >> 4;
                int c = (f & 15) * 4;
                int gr = min(blockRow + row, M - 1);
                float4 v = *(const float4*)((const float*)Av + (size_t)gr * K + k0 + c);
                union { bf16 h[4]; uint2 u; } tmp;
                tmp.h[0] = (bf16)v.x; tmp.h[1] = (bf16)v.y;
                tmp.h[2] = (bf16)v.z; tmp.h[3] = (bf16)v.w;
                *(uint2*)&As[row * LDK + c] = tmp.u;
            }
        }
        // B tile: Wt rows 0..127, k0..k0+63 : 1024 x 16B chunks; 4 per thread
#pragma unroll
        for (int l = 0; l < 4; ++l) {
            int f = tid + l * 256;
            int row = f >> 3;
            int c = (f & 7) * 8;
            uint4 v = *(const uint4*)(Wt + (size_t)row * K + k0 + c);
            *(uint4*)&Bs[row * LDK + c] = v;
        }
        __syncthreads();

#pragma unroll
        for (int ks = 0; ks < 4; ++ks) {
            const int koff = ks * 16 + lhi * 8;
            bf16x8 a = *(const bf16x8*)&As[(wv * 32 + l31) * LDK + koff];
#pragma unroll
            for (int t = 0; t < 4; ++t) {
                bf16x8 b = *(const bf16x8*)&Bs[(t * 32 + l31) * LDK + koff];
                acc[t] = __builtin_amdgcn_mfma_f32_32x32x16_bf16(a, b, acc[t], 0, 0, 0);
            }
        }
        __syncthreads();
    }

    // epilogue: C/D layout col=lane&31, row=(r&3)+8*(r>>2)+4*(lane>>5)
#pragma unroll
    for (int t = 0; t < 4; ++t) {
        int col = t * 32 + l31;
        float bcol = bias[col];
#pragma unroll
        for (int r = 0; r < 16; ++r) {
            int row = blockRow + wv * 32 + (r & 3) + 8 * (r >> 2) + 4 * lhi;
            if (row < M)
                C[(size_t)row * 128 + col] = (bf16)(acc[t][r] + bcol);
        }
    }
}

// ---------------------------------------------------------------------------
// Aggregation + ReLU on bf16 h. One wave per node; lane owns 2 features (4B).
// Indices/weights computed by lanes<40, broadcast via shuffle.
// ---------------------------------------------------------------------------
__global__ __launch_bounds__(256) void agg_relu(
    const bf16* __restrict__ hin, bf16* __restrict__ hout,
    const int* __restrict__ ends, const float* __restrict__ degree,
    const float* __restrict__ att)
{
    const int wv   = threadIdx.x >> 6;
    const int lane = threadIdx.x & 63;
    const int n    = blockIdx.x * 4 + wv;

    int   e = 0;
    float w = 0.0f;
    if (lane < KHOP * RWSAMP) {
        int k = lane / RWSAMP, s = lane - k * RWSAMP;
        e = ends[(size_t)k * (NNODES * RWSAMP) + (size_t)n * RWSAMP + s];
        w = att[k + 1] * (1.0f / RWSAMP) * sqrtf(degree[n]) * rsqrtf(degree[e]);
    }

    const int f = lane * 2;
    unsigned int u = *(const unsigned int*)(hin + (size_t)n * HID + f);
    float att0 = att[0];
    float acc0 = att0 * __uint_as_float(u << 16);
    float acc1 = att0 * __uint_as_float(u & 0xffff0000u);

#pragma unroll 8
    for (int j = 0; j < KHOP * RWSAMP; ++j) {
        int   ej = __shfl(e, j, 64);
        float wj = __shfl(w, j, 64);
        unsigned int uj = *(const unsigned int*)(hin + (size_t)ej * HID + f);
        acc0 = fmaf(wj, __uint_as_float(uj << 16), acc0);
        acc1 = fmaf(wj, __uint_as_float(uj & 0xffff0000u), acc1);
    }

    union { bf16 h[2]; unsigned int u; } st;
    st.h[0] = (bf16)fmaxf(acc0, 0.0f);
    st.h[1] = (bf16)fmaxf(acc1, 0.0f);
    *(unsigned int*)(hout + (size_t)n * HID + f) = st.u;
}

// ---------------------------------------------------------------------------
// Head: logits = h @ W2 + b2 ; log_softmax. One wave per node; h row staged
// to LDS as fp32; lane c<40 owns class c; shuffle reductions.
// ---------------------------------------------------------------------------
__global__ __launch_bounds__(256) void head_logsoftmax(
    const bf16* __restrict__ h, const float* __restrict__ W2,
    const float* __restrict__ b2, float* __restrict__ out)
{
    __shared__ float sh[4][HID];
    const int wv   = threadIdx.x >> 6;
    const int lane = threadIdx.x & 63;
    const int n    = blockIdx.x * 4 + wv;

    unsigned int u = *(const unsigned int*)(h + (size_t)n * HID + lane * 2);
    sh[wv][lane * 2 + 0] = __uint_as_float(u << 16);
    sh[wv][lane * 2 + 1] = __uint_as_float(u & 0xffff0000u);
    __syncthreads();

    float logit = -INFINITY;
    if (lane < NCLS) {
        float acc = b2[lane];
#pragma unroll 8
        for (int j = 0; j < HID; ++j)
            acc = fmaf(sh[wv][j], W2[j * NCLS + lane], acc);
        logit = acc;
    }

    float m = logit;
#pragma unroll
    for (int off = 32; off > 0; off >>= 1)
        m = fmaxf(m, __shfl_xor(m, off, 64));

    float e = (lane < NCLS) ? __expf(logit - m) : 0.0f;
    float s = e;
#pragma unroll
    for (int off = 32; off > 0; off >>= 1)
        s += __shfl_xor(s, off, 64);

    if (lane < NCLS)
        out[(size_t)n * NCLS + lane] = (logit - m) - __logf(s);
}

extern "C" void kernel_launch(void* const* d_in, const int* in_sizes, int n_in,
                              void* d_out, int out_size, void* d_ws, size_t ws_size,
                              hipStream_t stream)
{
    const float* x      = (const float*)d_in[0];
    const float* degree = (const float*)d_in[1];
    const int*   ends   = (const int*)  d_in[2];
    const float* att    = (const float*)d_in[3];
    const float* W0     = (const float*)d_in[4];
    const float* b0     = (const float*)d_in[5];
    const float* W1     = (const float*)d_in[6];
    const float* b1     = (const float*)d_in[7];
    const float* W2     = (const float*)d_in[8];
    const float* b2     = (const float*)d_in[9];
    float* out = (float*)d_out;

    bf16* hb0 = (bf16*)d_ws;                               // [NNODES, HID]
    bf16* hb1 = hb0 + (size_t)NNODES * HID;                // [NNODES, HID]
    bf16* Wt0 = hb1 + (size_t)NNODES * HID;                // [128, 256]
    bf16* Wt1 = Wt0 + 128 * 256;                           // [128, 128]

    prep_w<<<(128 * 256 + 128 * 128 + 255) / 256, 256, 0, stream>>>(W0, W1, Wt0, Wt1);

    const int gGemm = (NNODES + 127) / 128;

    // layer 0
    gemm_mfma<false><<<gGemm, 256, 0, stream>>>(x, Wt0, b0, hb0, NNODES, NFEAT);
    agg_relu<<<NNODES / 4, 256, 0, stream>>>(hb0, hb1, ends, degree, att);
    // layer 1
    gemm_mfma<true><<<gGemm, 256, 0, stream>>>(hb1, Wt1, b1, hb0, NNODES, HID);
    agg_relu<<<NNODES / 4, 256, 0, stream>>>(
        hb0, hb1, ends + (size_t)KHOP * NNODES * RWSAMP, degree, att + KP1);
    // head
    head_logsoftmax<<<NNODES / 4, 256, 0, stream>>>(hb1, W2, b2, out);
}

// Round 3
// 511.774 us; speedup vs baseline: 2.0245x; 1.1511x over previous
//
#include <hip/hip_runtime.h>
#include <math.h>

#define NNODES 100000
#define NFEAT  256
#define HID    128
#define NCLS   40
#define KHOP   4
#define RWSAMP 10
#define KP1    5

typedef __bf16 bf16;
typedef __attribute__((ext_vector_type(8)))  __bf16 bf16x8;
typedef __attribute__((ext_vector_type(16))) float  f32x16;

// ---------------------------------------------------------------------------
// Prep: transpose+convert weights to bf16 [n][k] layout.
// Wt0: 128x256, Wt1: 128x128, Wt2: 64x128 (cols 40..63 zero-padded).
// ---------------------------------------------------------------------------
__global__ __launch_bounds__(256) void prep_w(
    const float* __restrict__ W0, const float* __restrict__ W1,
    const float* __restrict__ W2,
    bf16* __restrict__ Wt0, bf16* __restrict__ Wt1, bf16* __restrict__ Wt2)
{
    int tid = blockIdx.x * 256 + threadIdx.x;
    if (tid < 128 * 256) {
        int n = tid >> 8, k = tid & 255;
        Wt0[tid] = (bf16)W0[k * 128 + n];
    } else if (tid < 128 * 256 + 128 * 128) {
        int i = tid - 128 * 256;
        int n = i >> 7, k = i & 127;
        Wt1[i] = (bf16)W1[k * 128 + n];
    } else if (tid < 128 * 256 + 128 * 128 + 64 * 128) {
        int i = tid - (128 * 256 + 128 * 128);
        int n = i >> 7, k = i & 127;
        Wt2[i] = (n < NCLS) ? (bf16)W2[k * NCLS + n] : (bf16)0.0f;
    }
}

// ---------------------------------------------------------------------------
// Barrier-free tall-skinny GEMM: C_bf16[M,128] = bf16(A @ W + bias)
// Whole Wt (<=64KB) staged once into padded LDS; A-frags direct from global.
// Block 256 = 4 waves; wave owns 32 rows; NT=4 col-tiles of 32.
// ---------------------------------------------------------------------------
template<int K, bool A_BF16>
__global__ __launch_bounds__(256) void gemm_nodes(
    const void* __restrict__ Av, const bf16* __restrict__ Wt,
    const float* __restrict__ bias, bf16* __restrict__ C, int M)
{
    constexpr int LDB = K + 8;            // pad: lane stride 4 banks -> 4-round b128
    __shared__ bf16 Bs[128 * LDB];

    const int tid = threadIdx.x;
    // stage ALL of Wt: 128 rows x K cols, 16B chunks
    constexpr int CPR = K / 8;            // chunks per row
    for (int f = tid; f < 128 * CPR; f += 256) {
        int row = f / CPR;
        int kc  = (f % CPR) * 8;
        *(uint4*)&Bs[row * LDB + kc] = *(const uint4*)(Wt + (size_t)row * K + kc);
    }
    __syncthreads();

    const int wv   = tid >> 6;
    const int lane = tid & 63;
    const int l31  = lane & 31;
    const int lhi  = lane >> 5;
    const int blockRow = blockIdx.x * 128;
    const int arow = min(blockRow + wv * 32 + l31, M - 1);

    const bf16*  Ab = (const bf16*)Av;
    const float* Af = (const float*)Av;

    f32x16 acc[4];
#pragma unroll
    for (int t = 0; t < 4; ++t)
#pragma unroll
        for (int r = 0; r < 16; ++r) acc[t][r] = 0.0f;

#pragma unroll 4
    for (int ks = 0; ks < K / 16; ++ks) {
        bf16x8 a;
        if (A_BF16) {
            a = *(const bf16x8*)(Ab + (size_t)arow * K + ks * 16 + lhi * 8);
        } else {
            const float4* p = (const float4*)(Af + (size_t)arow * K + ks * 16 + lhi * 8);
            float4 v0 = p[0], v1 = p[1];
            a[0] = (bf16)v0.x; a[1] = (bf16)v0.y; a[2] = (bf16)v0.z; a[3] = (bf16)v0.w;
            a[4] = (bf16)v1.x; a[5] = (bf16)v1.y; a[6] = (bf16)v1.z; a[7] = (bf16)v1.w;
        }
#pragma unroll
        for (int t = 0; t < 4; ++t) {
            bf16x8 b = *(const bf16x8*)&Bs[(t * 32 + l31) * LDB + ks * 16 + lhi * 8];
            acc[t] = __builtin_amdgcn_mfma_f32_32x32x16_bf16(a, b, acc[t], 0, 0, 0);
        }
    }

    // C/D layout: col=lane&31, row=(r&3)+8*(r>>2)+4*(lane>>5)
#pragma unroll
    for (int t = 0; t < 4; ++t) {
        int col = t * 32 + l31;
        float bc = bias[col];
#pragma unroll
        for (int r = 0; r < 16; ++r) {
            int grow = blockRow + wv * 32 + (r & 3) + 8 * (r >> 2) + 4 * lhi;
            if (grow < M)
                C[(size_t)grow * 128 + col] = (bf16)(acc[t][r] + bc);
        }
    }
}

// ---------------------------------------------------------------------------
// Aggregation + ReLU on bf16 h. One wave per node; lane owns 2 features.
// ---------------------------------------------------------------------------
__global__ __launch_bounds__(256) void agg_relu(
    const bf16* __restrict__ hin, bf16* __restrict__ hout,
    const int* __restrict__ ends, const float* __restrict__ degree,
    const float* __restrict__ att)
{
    const int wv   = threadIdx.x >> 6;
    const int lane = threadIdx.x & 63;
    const int n    = blockIdx.x * 4 + wv;

    int   e = 0;
    float w = 0.0f;
    if (lane < KHOP * RWSAMP) {
        int k = lane / RWSAMP, s = lane - k * RWSAMP;
        e = ends[(size_t)k * (NNODES * RWSAMP) + (size_t)n * RWSAMP + s];
        w = att[k + 1] * (1.0f / RWSAMP) * sqrtf(degree[n]) * rsqrtf(degree[e]);
    }

    const int f = lane * 2;
    unsigned int u = *(const unsigned int*)(hin + (size_t)n * HID + f);
    float att0 = att[0];
    float acc0 = att0 * __uint_as_float(u << 16);
    float acc1 = att0 * __uint_as_float(u & 0xffff0000u);

#pragma unroll 8
    for (int j = 0; j < KHOP * RWSAMP; ++j) {
        int   ej = __shfl(e, j, 64);
        float wj = __shfl(w, j, 64);
        unsigned int uj = *(const unsigned int*)(hin + (size_t)ej * HID + f);
        acc0 = fmaf(wj, __uint_as_float(uj << 16), acc0);
        acc1 = fmaf(wj, __uint_as_float(uj & 0xffff0000u), acc1);
    }

    union { bf16 h[2]; unsigned int u; } st;
    st.h[0] = (bf16)fmaxf(acc0, 0.0f);
    st.h[1] = (bf16)fmaxf(acc1, 0.0f);
    *(unsigned int*)(hout + (size_t)n * HID + f) = st.u;
}

// ---------------------------------------------------------------------------
// Head: logits = h @ W2 + b2 via MFMA (N=64, cols>=40 zero), log_softmax fused
// into the epilogue via 32-lane shuffle reductions. Writes d_out fp32 directly.
// ---------------------------------------------------------------------------
__global__ __launch_bounds__(256) void head_mfma(
    const bf16* __restrict__ h, const bf16* __restrict__ Wt2,
    const float* __restrict__ b2, float* __restrict__ out, int M)
{
    constexpr int K = HID, LDB = K + 8;
    __shared__ bf16 Bs[64 * LDB];

    const int tid = threadIdx.x;
    constexpr int CPR = K / 8;
    for (int f = tid; f < 64 * CPR; f += 256) {
        int row = f / CPR;
        int kc  = (f % CPR) * 8;
        *(uint4*)&Bs[row * LDB + kc] = *(const uint4*)(Wt2 + (size_t)row * K + kc);
    }
    __syncthreads();

    const int wv   = tid >> 6;
    const int lane = tid & 63;
    const int l31  = lane & 31;
    const int lhi  = lane >> 5;
    const int blockRow = blockIdx.x * 128;
    const int arow = min(blockRow + wv * 32 + l31, M - 1);

    f32x16 acc[2];
#pragma unroll
    for (int t = 0; t < 2; ++t)
#pragma unroll
        for (int r = 0; r < 16; ++r) acc[t][r] = 0.0f;

#pragma unroll
    for (int ks = 0; ks < K / 16; ++ks) {
        bf16x8 a = *(const bf16x8*)(h + (size_t)arow * K + ks * 16 + lhi * 8);
#pragma unroll
        for (int t = 0; t < 2; ++t) {
            bf16x8 b = *(const bf16x8*)&Bs[(t * 32 + l31) * LDB + ks * 16 + lhi * 8];
            acc[t] = __builtin_amdgcn_mfma_f32_32x32x16_bf16(a, b, acc[t], 0, 0, 0);
        }
    }

    const float bc0 = b2[l31];                          // cols 0..31
    const float bc1 = (l31 < 8) ? b2[32 + l31] : 0.0f;  // cols 32..39

#pragma unroll
    for (int r = 0; r < 16; ++r) {
        float v0 = acc[0][r] + bc0;
        float v1 = (l31 < 8) ? (acc[1][r] + bc1) : -INFINITY;

        float m = fmaxf(v0, v1);
#pragma unroll
        for (int off = 16; off > 0; off >>= 1)
            m = fmaxf(m, __shfl_xor(m, off, 64));

        float s = __expf(v0 - m) + ((l31 < 8) ? __expf(v1 - m) : 0.0f);
#pragma unroll
        for (int off = 16; off > 0; off >>= 1)
            s += __shfl_xor(s, off, 64);

        float ls = __logf(s);
        int grow = blockRow + wv * 32 + (r & 3) + 8 * (r >> 2) + 4 * lhi;
        if (grow < M) {
            out[(size_t)grow * NCLS + l31] = v0 - m - ls;
            if (l31 < 8)
                out[(size_t)grow * NCLS + 32 + l31] = v1 - m - ls;
        }
    }
}

extern "C" void kernel_launch(void* const* d_in, const int* in_sizes, int n_in,
                              void* d_out, int out_size, void* d_ws, size_t ws_size,
                              hipStream_t stream)
{
    const float* x      = (const float*)d_in[0];
    const float* degree = (const float*)d_in[1];
    const int*   ends   = (const int*)  d_in[2];
    const float* att    = (const float*)d_in[3];
    const float* W0     = (const float*)d_in[4];
    const float* b0     = (const float*)d_in[5];
    const float* W1     = (const float*)d_in[6];
    const float* b1     = (const float*)d_in[7];
    const float* W2     = (const float*)d_in[8];
    const float* b2     = (const float*)d_in[9];
    float* out = (float*)d_out;

    bf16* hb0 = (bf16*)d_ws;                               // [NNODES, HID]
    bf16* hb1 = hb0 + (size_t)NNODES * HID;                // [NNODES, HID]
    bf16* Wt0 = hb1 + (size_t)NNODES * HID;                // [128, 256]
    bf16* Wt1 = Wt0 + 128 * 256;                           // [128, 128]
    bf16* Wt2 = Wt1 + 128 * 128;                           // [64, 128]

    const int prepN = 128 * 256 + 128 * 128 + 64 * 128;
    prep_w<<<(prepN + 255) / 256, 256, 0, stream>>>(W0, W1, W2, Wt0, Wt1, Wt2);

    const int gGemm = (NNODES + 127) / 128;

    // layer 0
    gemm_nodes<NFEAT, false><<<gGemm, 256, 0, stream>>>(x, Wt0, b0, hb0, NNODES);
    agg_relu<<<NNODES / 4, 256, 0, stream>>>(hb0, hb1, ends, degree, att);
    // layer 1
    gemm_nodes<HID, true><<<gGemm, 256, 0, stream>>>(hb1, Wt1, b1, hb0, NNODES);
    agg_relu<<<NNODES / 4, 256, 0, stream>>>(
        hb0, hb1, ends + (size_t)KHOP * NNODES * RWSAMP, degree, att + KP1);
    // head
    head_mfma<<<gGemm, 256, 0, stream>>>(hb1, Wt2, b2, out, NNODES);
}

// Round 4
// 431.625 us; speedup vs baseline: 2.4004x; 1.1857x over previous
//
#include <hip/hip_runtime.h>
#include <math.h>

#define NNODES 100000
#define NFEAT  256
#define HID    128
#define NCLS   40
#define KHOP   4
#define RWSAMP 10
#define KP1    5

typedef __bf16 bf16;
typedef __attribute__((ext_vector_type(8)))  __bf16 bf16x8;
typedef __attribute__((ext_vector_type(2)))  float  f32x2;
typedef __attribute__((ext_vector_type(16))) float  f32x16;

// ---------------------------------------------------------------------------
// Prep: transpose+convert weights to bf16 [n][k] layout.
// Wt0: 128x256, Wt1: 128x128, Wt2: 64x128 (cols 40..63 zero-padded).
// ---------------------------------------------------------------------------
__global__ __launch_bounds__(256) void prep_w(
    const float* __restrict__ W0, const float* __restrict__ W1,
    const float* __restrict__ W2,
    bf16* __restrict__ Wt0, bf16* __restrict__ Wt1, bf16* __restrict__ Wt2)
{
    int tid = blockIdx.x * 256 + threadIdx.x;
    if (tid < 128 * 256) {
        int n = tid >> 8, k = tid & 255;
        Wt0[tid] = (bf16)W0[k * 128 + n];
    } else if (tid < 128 * 256 + 128 * 128) {
        int i = tid - 128 * 256;
        int n = i >> 7, k = i & 127;
        Wt1[i] = (bf16)W1[k * 128 + n];
    } else if (tid < 128 * 256 + 128 * 128 + 64 * 128) {
        int i = tid - (128 * 256 + 128 * 128);
        int n = i >> 7, k = i & 127;
        Wt2[i] = (n < NCLS) ? (bf16)W2[k * NCLS + n] : (bf16)0.0f;
    }
}

// ---------------------------------------------------------------------------
// bf16 -> fp8 e4m3 stream convert (4 elems/thread).
// ---------------------------------------------------------------------------
__global__ __launch_bounds__(256) void to_fp8(
    const bf16* __restrict__ in, unsigned int* __restrict__ out, int n4)
{
    int i = blockIdx.x * 256 + threadIdx.x;
    if (i >= n4) return;
    uint2 u = *(const uint2*)(in + (size_t)i * 4);
    float f0 = __uint_as_float(u.x << 16);
    float f1 = __uint_as_float(u.x & 0xffff0000u);
    float f2 = __uint_as_float(u.y << 16);
    float f3 = __uint_as_float(u.y & 0xffff0000u);
    int p = __builtin_amdgcn_cvt_pk_fp8_f32(f0, f1, 0, false);   // bytes 0,1
    p = __builtin_amdgcn_cvt_pk_fp8_f32(f2, f3, p, true);        // bytes 2,3
    out[i] = (unsigned int)p;
}

// ---------------------------------------------------------------------------
// GEMM: C_bf16[M,128] = bf16(A @ W + bias). MFMA 32x32x16 bf16.
// Block 256 = 4 waves; M-tile 128 (32 rows/wave); W streamed in BK=128
// chunks (coop staged, barriered); A staged per-wave into PRIVATE LDS with
// fully coalesced global loads (no cross-wave barrier needed).
// LDS row stride 132 elems (264B = 66 dw == 2 mod 4): 2-way-free bank pattern.
// ---------------------------------------------------------------------------
template<int K, bool A_BF16>
__global__ __launch_bounds__(256) void gemm_nodes(
    const void* __restrict__ Av, const bf16* __restrict__ Wt,
    const float* __restrict__ bias, bf16* __restrict__ C, int M)
{
    constexpr int BK  = 128;
    constexpr int LDB = BK + 4;                 // 132 elems = 264 B
    __shared__ bf16 Bs[128 * LDB];              // W chunk [n][k]
    __shared__ bf16 As[4][32 * LDB];            // per-wave A chunk [r][k]

    const int tid  = threadIdx.x;
    const int wv   = tid >> 6;
    const int lane = tid & 63;
    const int l31  = lane & 31;
    const int lhi  = lane >> 5;
    const int blockRow = blockIdx.x * 128;
    const int rowBase  = blockRow + wv * 32;

    const bf16*  Ab = (const bf16*)Av;
    const float* Af = (const float*)Av;

    f32x16 acc[4];
#pragma unroll
    for (int t = 0; t < 4; ++t)
#pragma unroll
        for (int r = 0; r < 16; ++r) acc[t][r] = 0.0f;

    for (int k0 = 0; k0 < K; k0 += BK) {
        if (k0) __syncthreads();                 // all waves done reading Bs
        // ---- stage W chunk: 128 n x 128 k, 16B/thread x 8 rounds ----
#pragma unroll 4
        for (int l = 0; l < 8; ++l) {
            int c   = tid + l * 256;             // chunk id; 16 chunks/row
            int row = c >> 4;
            int kc  = (c & 15) * 8;
            uint4 v = *(const uint4*)(Wt + (size_t)row * K + k0 + kc);
            *(uint2*)&Bs[row * LDB + kc]     = make_uint2(v.x, v.y);
            *(uint2*)&Bs[row * LDB + kc + 4] = make_uint2(v.z, v.w);
        }
        __syncthreads();

        // ---- stage A per-wave (coalesced; private region, no barrier) ----
        if (A_BF16) {
#pragma unroll 4
            for (int l = 0; l < 8; ++l) {
                int c  = lane + l * 64;          // 32 rows x 16 chunks
                int r  = c >> 4;
                int kc = (c & 15) * 8;
                int gr = min(rowBase + r, M - 1);
                uint4 v = *(const uint4*)(Ab + (size_t)gr * K + k0 + kc);
                *(uint2*)&As[wv][r * LDB + kc]     = make_uint2(v.x, v.y);
                *(uint2*)&As[wv][r * LDB + kc + 4] = make_uint2(v.z, v.w);
            }
        } else {
#pragma unroll 4
            for (int l = 0; l < 16; ++l) {
                int c  = lane + l * 64;          // 32 rows x 32 float4-chunks
                int r  = c >> 5;
                int kc = (c & 31) * 4;
                int gr = min(rowBase + r, M - 1);
                float4 v = *(const float4*)(Af + (size_t)gr * K + k0 + kc);
                union { bf16 h[4]; uint2 u; } t4;
                t4.h[0] = (bf16)v.x; t4.h[1] = (bf16)v.y;
                t4.h[2] = (bf16)v.z; t4.h[3] = (bf16)v.w;
                *(uint2*)&As[wv][r * LDB + kc] = t4.u;
            }
        }

        // ---- compute ----
#pragma unroll
        for (int ks = 0; ks < BK / 16; ++ks) {
            const int ko = ks * 16 + lhi * 8;
            union { uint2 u2[2]; bf16x8 v; } ua, ub;
            ua.u2[0] = *(const uint2*)&As[wv][l31 * LDB + ko];
            ua.u2[1] = *(const uint2*)&As[wv][l31 * LDB + ko + 4];
            bf16x8 a = ua.v;
#pragma unroll
            for (int t = 0; t < 4; ++t) {
                ub.u2[0] = *(const uint2*)&Bs[(t * 32 + l31) * LDB + ko];
                ub.u2[1] = *(const uint2*)&Bs[(t * 32 + l31) * LDB + ko + 4];
                acc[t] = __builtin_amdgcn_mfma_f32_32x32x16_bf16(a, ub.v, acc[t], 0, 0, 0);
            }
        }
    }

    // C/D layout: col=lane&31, row=(r&3)+8*(r>>2)+4*(lane>>5)
#pragma unroll
    for (int t = 0; t < 4; ++t) {
        int col = t * 32 + l31;
        float bc = bias[col];
#pragma unroll
        for (int r = 0; r < 16; ++r) {
            int grow = blockRow + wv * 32 + (r & 3) + 8 * (r >> 2) + 4 * lhi;
            if (grow < M)
                C[(size_t)grow * 128 + col] = (bf16)(acc[t][r] + bc);
        }
    }
}

// ---------------------------------------------------------------------------
// Aggregation + ReLU. Self-term from bf16 h; gathers from fp8 e4m3 h (half
// the random-read bytes). One wave per node; lane owns 2 features.
// ---------------------------------------------------------------------------
__global__ __launch_bounds__(256) void agg_relu_fp8(
    const bf16* __restrict__ hbf, const unsigned char* __restrict__ hf8,
    bf16* __restrict__ hout,
    const int* __restrict__ ends, const float* __restrict__ degree,
    const float* __restrict__ att)
{
    const int wv   = threadIdx.x >> 6;
    const int lane = threadIdx.x & 63;
    const int n    = blockIdx.x * 4 + wv;

    int   e = 0;
    float w = 0.0f;
    if (lane < KHOP * RWSAMP) {
        int k = lane / RWSAMP, s = lane - k * RWSAMP;
        e = ends[(size_t)k * (NNODES * RWSAMP) + (size_t)n * RWSAMP + s];
        w = att[k + 1] * (1.0f / RWSAMP) * sqrtf(degree[n]) * rsqrtf(degree[e]);
    }

    const int f = lane * 2;
    unsigned int u = *(const unsigned int*)(hbf + (size_t)n * HID + f);
    float att0 = att[0];
    float acc0 = att0 * __uint_as_float(u << 16);
    float acc1 = att0 * __uint_as_float(u & 0xffff0000u);

#pragma unroll 8
    for (int j = 0; j < KHOP * RWSAMP; ++j) {
        int   ej = __shfl(e, j, 64);
        float wj = __shfl(w, j, 64);
        unsigned short us = *(const unsigned short*)(hf8 + (size_t)ej * HID + f);
        f32x2 g = __builtin_amdgcn_cvt_pk_f32_fp8((int)us, false);
        acc0 = fmaf(wj, g.x, acc0);
        acc1 = fmaf(wj, g.y, acc1);
    }

    union { bf16 h[2]; unsigned int u; } st;
    st.h[0] = (bf16)fmaxf(acc0, 0.0f);
    st.h[1] = (bf16)fmaxf(acc1, 0.0f);
    *(unsigned int*)(hout + (size_t)n * HID + f) = st.u;
}

// ---------------------------------------------------------------------------
// Head: logits = h @ W2 + b2 via MFMA (N=64, cols>=40 zero), fused log_softmax.
// ---------------------------------------------------------------------------
__global__ __launch_bounds__(256) void head_mfma(
    const bf16* __restrict__ h, const bf16* __restrict__ Wt2,
    const float* __restrict__ b2, float* __restrict__ out, int M)
{
    constexpr int K = HID, LDB = K + 8;
    __shared__ bf16 Bs[64 * LDB];

    const int tid = threadIdx.x;
    constexpr int CPR = K / 8;
    for (int f = tid; f < 64 * CPR; f += 256) {
        int row = f / CPR;
        int kc  = (f % CPR) * 8;
        *(uint4*)&Bs[row * LDB + kc] = *(const uint4*)(Wt2 + (size_t)row * K + kc);
    }
    __syncthreads();

    const int wv   = tid >> 6;
    const int lane = tid & 63;
    const int l31  = lane & 31;
    const int lhi  = lane >> 5;
    const int blockRow = blockIdx.x * 128;
    const int arow = min(blockRow + wv * 32 + l31, M - 1);

    f32x16 acc[2];
#pragma unroll
    for (int t = 0; t < 2; ++t)
#pragma unroll
        for (int r = 0; r < 16; ++r) acc[t][r] = 0.0f;

#pragma unroll
    for (int ks = 0; ks < K / 16; ++ks) {
        bf16x8 a = *(const bf16x8*)(h + (size_t)arow * K + ks * 16 + lhi * 8);
#pragma unroll
        for (int t = 0; t < 2; ++t) {
            bf16x8 b = *(const bf16x8*)&Bs[(t * 32 + l31) * LDB + ks * 16 + lhi * 8];
            acc[t] = __builtin_amdgcn_mfma_f32_32x32x16_bf16(a, b, acc[t], 0, 0, 0);
        }
    }

    const float bc0 = b2[l31];
    const float bc1 = (l31 < 8) ? b2[32 + l31] : 0.0f;

#pragma unroll
    for (int r = 0; r < 16; ++r) {
        float v0 = acc[0][r] + bc0;
        float v1 = (l31 < 8) ? (acc[1][r] + bc1) : -INFINITY;

        float m = fmaxf(v0, v1);
#pragma unroll
        for (int off = 16; off > 0; off >>= 1)
            m = fmaxf(m, __shfl_xor(m, off, 64));

        float s = __expf(v0 - m) + ((l31 < 8) ? __expf(v1 - m) : 0.0f);
#pragma unroll
        for (int off = 16; off > 0; off >>= 1)
            s += __shfl_xor(s, off, 64);

        float ls = __logf(s);
        int grow = blockRow + wv * 32 + (r & 3) + 8 * (r >> 2) + 4 * lhi;
        if (grow < M) {
            out[(size_t)grow * NCLS + l31] = v0 - m - ls;
            if (l31 < 8)
                out[(size_t)grow * NCLS + 32 + l31] = v1 - m - ls;
        }
    }
}

extern "C" void kernel_launch(void* const* d_in, const int* in_sizes, int n_in,
                              void* d_out, int out_size, void* d_ws, size_t ws_size,
                              hipStream_t stream)
{
    const float* x      = (const float*)d_in[0];
    const float* degree = (const float*)d_in[1];
    const int*   ends   = (const int*)  d_in[2];
    const float* att    = (const float*)d_in[3];
    const float* W0     = (const float*)d_in[4];
    const float* b0     = (const float*)d_in[5];
    const float* W1     = (const float*)d_in[6];
    const float* b1     = (const float*)d_in[7];
    const float* W2     = (const float*)d_in[8];
    const float* b2     = (const float*)d_in[9];
    float* out = (float*)d_out;

    bf16* hb0 = (bf16*)d_ws;                               // [NNODES, HID] bf16
    bf16* hb1 = hb0 + (size_t)NNODES * HID;                // [NNODES, HID] bf16
    unsigned char* hf8 = (unsigned char*)(hb1 + (size_t)NNODES * HID);  // [NNODES, HID] fp8
    bf16* Wt0 = (bf16*)(hf8 + (size_t)NNODES * HID);       // [128, 256]
    bf16* Wt1 = Wt0 + 128 * 256;                           // [128, 128]
    bf16* Wt2 = Wt1 + 128 * 128;                           // [64, 128]

    const int prepN = 128 * 256 + 128 * 128 + 64 * 128;
    prep_w<<<(prepN + 255) / 256, 256, 0, stream>>>(W0, W1, W2, Wt0, Wt1, Wt2);

    const int gGemm = (NNODES + 127) / 128;
    const int n4    = NNODES * HID / 4;
    const int gCvt  = (n4 + 255) / 256;

    // layer 0
    gemm_nodes<NFEAT, false><<<gGemm, 256, 0, stream>>>(x, Wt0, b0, hb0, NNODES);
    to_fp8<<<gCvt, 256, 0, stream>>>(hb0, (unsigned int*)hf8, n4);
    agg_relu_fp8<<<NNODES / 4, 256, 0, stream>>>(hb0, hf8, hb1, ends, degree, att);
    // layer 1
    gemm_nodes<HID, true><<<gGemm, 256, 0, stream>>>(hb1, Wt1, b1, hb0, NNODES);
    to_fp8<<<gCvt, 256, 0, stream>>>(hb0, (unsigned int*)hf8, n4);
    agg_relu_fp8<<<NNODES / 4, 256, 0, stream>>>(
        hb0, hf8, hb1, ends + (size_t)KHOP * NNODES * RWSAMP, degree, att + KP1);
    // head
    head_mfma<<<gGemm, 256, 0, stream>>>(hb1, Wt2, b2, out, NNODES);
}

// Round 5
// 366.580 us; speedup vs baseline: 2.8263x; 1.1774x over previous
//
#include <hip/hip_runtime.h>
#include <math.h>

#define NNODES 100000
#define NFEAT  256
#define HID    128
#define NCLS   40
#define KHOP   4
#define RWSAMP 10
#define KP1    5

typedef __bf16 bf16;
typedef __attribute__((ext_vector_type(8)))  __bf16 bf16x8;
typedef __attribute__((ext_vector_type(2)))  float  f32x2;
typedef __attribute__((ext_vector_type(16))) float  f32x16;

// ---------------------------------------------------------------------------
// Prep: transpose+convert weights to bf16 [n][k] layout.
// ---------------------------------------------------------------------------
__global__ __launch_bounds__(256) void prep_w(
    const float* __restrict__ W0, const float* __restrict__ W1,
    const float* __restrict__ W2,
    bf16* __restrict__ Wt0, bf16* __restrict__ Wt1, bf16* __restrict__ Wt2)
{
    int tid = blockIdx.x * 256 + threadIdx.x;
    if (tid < 128 * 256) {
        int n = tid >> 8, k = tid & 255;
        Wt0[tid] = (bf16)W0[k * 128 + n];
    } else if (tid < 128 * 256 + 128 * 128) {
        int i = tid - 128 * 256;
        int n = i >> 7, k = i & 127;
        Wt1[i] = (bf16)W1[k * 128 + n];
    } else if (tid < 128 * 256 + 128 * 128 + 64 * 128) {
        int i = tid - (128 * 256 + 128 * 128);
        int n = i >> 7, k = i & 127;
        Wt2[i] = (n < NCLS) ? (bf16)W2[k * NCLS + n] : (bf16)0.0f;
    }
}

// ---------------------------------------------------------------------------
// GEMM: MFMA 32x32x16 bf16; writes BOTH bf16 C and a row-major fp8-e4m3 copy
// (fp8 emitted via LDS 4x4 byte-transpose -> coalesced dword stores).
// Block 256 = 4 waves; M-tile 128; W streamed in BK=128 chunks; A staged
// per-wave (private LDS region, no cross-wave barrier).
// ---------------------------------------------------------------------------
template<int K, bool A_BF16>
__global__ __launch_bounds__(256) void gemm_nodes(
    const void* __restrict__ Av, const bf16* __restrict__ Wt,
    const float* __restrict__ bias, bf16* __restrict__ C,
    unsigned char* __restrict__ F8, int M)
{
    constexpr int BK  = 128;
    constexpr int LDB = BK + 4;                 // 132 elems = 264 B
    __shared__ bf16 Bs[128 * LDB];              // W chunk [n][k]
    __shared__ bf16 As[4][32 * LDB];            // per-wave A chunk [r][k]

    const int tid  = threadIdx.x;
    const int wv   = tid >> 6;
    const int lane = tid & 63;
    const int l31  = lane & 31;
    const int lhi  = lane >> 5;
    const int blockRow = blockIdx.x * 128;
    const int rowBase  = blockRow + wv * 32;

    const bf16*  Ab = (const bf16*)Av;
    const float* Af = (const float*)Av;

    f32x16 acc[4];
#pragma unroll
    for (int t = 0; t < 4; ++t)
#pragma unroll
        for (int r = 0; r < 16; ++r) acc[t][r] = 0.0f;

    for (int k0 = 0; k0 < K; k0 += BK) {
        if (k0) __syncthreads();
        // ---- stage W chunk ----
#pragma unroll 4
        for (int l = 0; l < 8; ++l) {
            int c   = tid + l * 256;
            int row = c >> 4;
            int kc  = (c & 15) * 8;
            uint4 v = *(const uint4*)(Wt + (size_t)row * K + k0 + kc);
            *(uint2*)&Bs[row * LDB + kc]     = make_uint2(v.x, v.y);
            *(uint2*)&Bs[row * LDB + kc + 4] = make_uint2(v.z, v.w);
        }
        __syncthreads();

        // ---- stage A per-wave ----
        if (A_BF16) {
#pragma unroll 4
            for (int l = 0; l < 8; ++l) {
                int c  = lane + l * 64;
                int r  = c >> 4;
                int kc = (c & 15) * 8;
                int gr = min(rowBase + r, M - 1);
                uint4 v = *(const uint4*)(Ab + (size_t)gr * K + k0 + kc);
                *(uint2*)&As[wv][r * LDB + kc]     = make_uint2(v.x, v.y);
                *(uint2*)&As[wv][r * LDB + kc + 4] = make_uint2(v.z, v.w);
            }
        } else {
#pragma unroll 4
            for (int l = 0; l < 16; ++l) {
                int c  = lane + l * 64;
                int r  = c >> 5;
                int kc = (c & 31) * 4;
                int gr = min(rowBase + r, M - 1);
                float4 v = *(const float4*)(Af + (size_t)gr * K + k0 + kc);
                union { bf16 h[4]; uint2 u; } t4;
                t4.h[0] = (bf16)v.x; t4.h[1] = (bf16)v.y;
                t4.h[2] = (bf16)v.z; t4.h[3] = (bf16)v.w;
                *(uint2*)&As[wv][r * LDB + kc] = t4.u;
            }
        }

        // ---- compute ----
#pragma unroll
        for (int ks = 0; ks < BK / 16; ++ks) {
            const int ko = ks * 16 + lhi * 8;
            union { uint2 u2[2]; bf16x8 v; } ua, ub;
            ua.u2[0] = *(const uint2*)&As[wv][l31 * LDB + ko];
            ua.u2[1] = *(const uint2*)&As[wv][l31 * LDB + ko + 4];
            bf16x8 a = ua.v;
#pragma unroll
            for (int t = 0; t < 4; ++t) {
                ub.u2[0] = *(const uint2*)&Bs[(t * 32 + l31) * LDB + ko];
                ub.u2[1] = *(const uint2*)&Bs[(t * 32 + l31) * LDB + ko + 4];
                acc[t] = __builtin_amdgcn_mfma_f32_32x32x16_bf16(a, ub.v, acc[t], 0, 0, 0);
            }
        }
    }

    __syncthreads();                // all waves done reading Bs before overlay
    unsigned* ldsq = (unsigned*)Bs; // [32 rowquads][128 cols] dwords (16 KB)

    // epilogue: bf16 C store + fp8 pack (4 rows/dword) into LDS
#pragma unroll
    for (int t = 0; t < 4; ++t) {
        int col = t * 32 + l31;
        float bc = bias[col];
#pragma unroll
        for (int G = 0; G < 4; ++G) {
            int rowb = blockRow + wv * 32 + 8 * G + 4 * lhi;
            float v0 = acc[t][4 * G + 0] + bc;
            float v1 = acc[t][4 * G + 1] + bc;
            float v2 = acc[t][4 * G + 2] + bc;
            float v3 = acc[t][4 * G + 3] + bc;
            if (rowb + 0 < M) C[(size_t)(rowb + 0) * 128 + col] = (bf16)v0;
            if (rowb + 1 < M) C[(size_t)(rowb + 1) * 128 + col] = (bf16)v1;
            if (rowb + 2 < M) C[(size_t)(rowb + 2) * 128 + col] = (bf16)v2;
            if (rowb + 3 < M) C[(size_t)(rowb + 3) * 128 + col] = (bf16)v3;
            int p = __builtin_amdgcn_cvt_pk_fp8_f32(v0, v1, 0, false);
            p = __builtin_amdgcn_cvt_pk_fp8_f32(v2, v3, p, true);
            ldsq[(wv * 8 + 2 * G + lhi) * 128 + col] = (unsigned)p;
        }
    }
    __syncthreads();

    // readout: 4x4 byte-transpose via v_perm, coalesced dword stores
    {
        const int j  = tid & 31;
        const int Q0 = (tid >> 5) * 4;
#pragma unroll
        for (int qq = 0; qq < 4; ++qq) {
            int Q = Q0 + qq;
            uint4 d = *(const uint4*)&ldsq[Q * 128 + 4 * j];
            int growb = blockRow + 4 * Q;
#pragma unroll
            for (int i = 0; i < 4; ++i) {
                unsigned sel = ((unsigned)(4 + i) << 8) | (unsigned)i;
                unsigned lo = __builtin_amdgcn_perm(d.y, d.x, sel);
                unsigned hi = __builtin_amdgcn_perm(d.w, d.z, sel);
                unsigned o  = __builtin_amdgcn_perm(hi, lo, 0x05040100u);
                if (growb + i < M)
                    *(unsigned*)(F8 + (size_t)(growb + i) * 128 + 4 * j) = o;
            }
        }
    }
}

// ---------------------------------------------------------------------------
// Aggregation + ReLU. One wave per node. Lane-quarter q handles row 4t+q;
// each lane loads 8 fp8 feats (dwordx2). (e,w) staged in wave-private LDS.
// Butterfly (xor 16,32) combines quarters; self-term bf16 on lanes 0-15.
// ---------------------------------------------------------------------------
__global__ __launch_bounds__(256) void agg_relu_fp8(
    const bf16* __restrict__ hbf, const unsigned char* __restrict__ hf8,
    bf16* __restrict__ hout,
    const int* __restrict__ ends, const float* __restrict__ degree,
    const float* __restrict__ att)
{
    __shared__ int   se[4][40];
    __shared__ float sw[4][40];

    const int wv   = threadIdx.x >> 6;
    const int lane = threadIdx.x & 63;
    const int n    = blockIdx.x * 4 + wv;

    if (lane < KHOP * RWSAMP) {
        int k = lane / RWSAMP, s = lane - k * RWSAMP;
        int e = ends[(size_t)k * (NNODES * RWSAMP) + (size_t)n * RWSAMP + s];
        se[wv][lane] = e;
        sw[wv][lane] = att[k + 1] * (1.0f / RWSAMP) * sqrtf(degree[n]) * rsqrtf(degree[e]);
    }
    // wave-private LDS region: same-wave producer/consumer, no barrier needed

    const int q  = lane >> 4;          // row-within-group
    const int c8 = (lane & 15) * 8;    // feature offset (8 feats/lane)

    float acc[8];
#pragma unroll
    for (int i = 0; i < 8; ++i) acc[i] = 0.0f;

#pragma unroll
    for (int t = 0; t < 10; ++t) {
        int   jj = 4 * t + q;
        int   ej = se[wv][jj];
        float wj = sw[wv][jj];
        uint2 g = *(const uint2*)(hf8 + (size_t)ej * HID + c8);
        f32x2 p0 = __builtin_amdgcn_cvt_pk_f32_fp8((int)g.x, false);
        f32x2 p1 = __builtin_amdgcn_cvt_pk_f32_fp8((int)g.x, true);
        f32x2 p2 = __builtin_amdgcn_cvt_pk_f32_fp8((int)g.y, false);
        f32x2 p3 = __builtin_amdgcn_cvt_pk_f32_fp8((int)g.y, true);
        acc[0] = fmaf(wj, p0.x, acc[0]);
        acc[1] = fmaf(wj, p0.y, acc[1]);
        acc[2] = fmaf(wj, p1.x, acc[2]);
        acc[3] = fmaf(wj, p1.y, acc[3]);
        acc[4] = fmaf(wj, p2.x, acc[4]);
        acc[5] = fmaf(wj, p2.y, acc[5]);
        acc[6] = fmaf(wj, p3.x, acc[6]);
        acc[7] = fmaf(wj, p3.y, acc[7]);
    }

    // combine quarters
#pragma unroll
    for (int i = 0; i < 8; ++i) {
        acc[i] += __shfl_xor(acc[i], 16, 64);
        acc[i] += __shfl_xor(acc[i], 32, 64);
    }

    if (q == 0) {
        uint4 su = *(const uint4*)(hbf + (size_t)n * HID + c8);
        float att0 = att[0];
        float s0 = __uint_as_float(su.x << 16);
        float s1 = __uint_as_float(su.x & 0xffff0000u);
        float s2 = __uint_as_float(su.y << 16);
        float s3 = __uint_as_float(su.y & 0xffff0000u);
        float s4 = __uint_as_float(su.z << 16);
        float s5 = __uint_as_float(su.z & 0xffff0000u);
        float s6 = __uint_as_float(su.w << 16);
        float s7 = __uint_as_float(su.w & 0xffff0000u);
        union { bf16 h[8]; uint4 u; } st;
        st.h[0] = (bf16)fmaxf(fmaf(att0, s0, acc[0]), 0.0f);
        st.h[1] = (bf16)fmaxf(fmaf(att0, s1, acc[1]), 0.0f);
        st.h[2] = (bf16)fmaxf(fmaf(att0, s2, acc[2]), 0.0f);
        st.h[3] = (bf16)fmaxf(fmaf(att0, s3, acc[3]), 0.0f);
        st.h[4] = (bf16)fmaxf(fmaf(att0, s4, acc[4]), 0.0f);
        st.h[5] = (bf16)fmaxf(fmaf(att0, s5, acc[5]), 0.0f);
        st.h[6] = (bf16)fmaxf(fmaf(att0, s6, acc[6]), 0.0f);
        st.h[7] = (bf16)fmaxf(fmaf(att0, s7, acc[7]), 0.0f);
        *(uint4*)(hout + (size_t)n * HID + c8) = st.u;
    }
}

// ---------------------------------------------------------------------------
// Head: logits = h @ W2 + b2 via MFMA (N=64, cols>=40 zero), fused log_softmax.
// ---------------------------------------------------------------------------
__global__ __launch_bounds__(256) void head_mfma(
    const bf16* __restrict__ h, const bf16* __restrict__ Wt2,
    const float* __restrict__ b2, float* __restrict__ out, int M)
{
    constexpr int K = HID, LDB = K + 8;
    __shared__ bf16 Bs[64 * LDB];

    const int tid = threadIdx.x;
    constexpr int CPR = K / 8;
    for (int f = tid; f < 64 * CPR; f += 256) {
        int row = f / CPR;
        int kc  = (f % CPR) * 8;
        *(uint4*)&Bs[row * LDB + kc] = *(const uint4*)(Wt2 + (size_t)row * K + kc);
    }
    __syncthreads();

    const int wv   = tid >> 6;
    const int lane = tid & 63;
    const int l31  = lane & 31;
    const int lhi  = lane >> 5;
    const int blockRow = blockIdx.x * 128;
    const int arow = min(blockRow + wv * 32 + l31, M - 1);

    f32x16 acc[2];
#pragma unroll
    for (int t = 0; t < 2; ++t)
#pragma unroll
        for (int r = 0; r < 16; ++r) acc[t][r] = 0.0f;

#pragma unroll
    for (int ks = 0; ks < K / 16; ++ks) {
        bf16x8 a = *(const bf16x8*)(h + (size_t)arow * K + ks * 16 + lhi * 8);
#pragma unroll
        for (int t = 0; t < 2; ++t) {
            bf16x8 b = *(const bf16x8*)&Bs[(t * 32 + l31) * LDB + ks * 16 + lhi * 8];
            acc[t] = __builtin_amdgcn_mfma_f32_32x32x16_bf16(a, b, acc[t], 0, 0, 0);
        }
    }

    const float bc0 = b2[l31];
    const float bc1 = (l31 < 8) ? b2[32 + l31] : 0.0f;

#pragma unroll
    for (int r = 0; r < 16; ++r) {
        float v0 = acc[0][r] + bc0;
        float v1 = (l31 < 8) ? (acc[1][r] + bc1) : -INFINITY;

        float m = fmaxf(v0, v1);
#pragma unroll
        for (int off = 16; off > 0; off >>= 1)
            m = fmaxf(m, __shfl_xor(m, off, 64));

        float s = __expf(v0 - m) + ((l31 < 8) ? __expf(v1 - m) : 0.0f);
#pragma unroll
        for (int off = 16; off > 0; off >>= 1)
            s += __shfl_xor(s, off, 64);

        float ls = __logf(s);
        int grow = blockRow + wv * 32 + (r & 3) + 8 * (r >> 2) + 4 * lhi;
        if (grow < M) {
            out[(size_t)grow * NCLS + l31] = v0 - m - ls;
            if (l31 < 8)
                out[(size_t)grow * NCLS + 32 + l31] = v1 - m - ls;
        }
    }
}

extern "C" void kernel_launch(void* const* d_in, const int* in_sizes, int n_in,
                              void* d_out, int out_size, void* d_ws, size_t ws_size,
                              hipStream_t stream)
{
    const float* x      = (const float*)d_in[0];
    const float* degree = (const float*)d_in[1];
    const int*   ends   = (const int*)  d_in[2];
    const float* att    = (const float*)d_in[3];
    const float* W0     = (const float*)d_in[4];
    const float* b0     = (const float*)d_in[5];
    const float* W1     = (const float*)d_in[6];
    const float* b1     = (const float*)d_in[7];
    const float* W2     = (const float*)d_in[8];
    const float* b2     = (const float*)d_in[9];
    float* out = (float*)d_out;

    bf16* hb0 = (bf16*)d_ws;                               // [NNODES, HID] bf16
    bf16* hb1 = hb0 + (size_t)NNODES * HID;                // [NNODES, HID] bf16
    unsigned char* hf8 = (unsigned char*)(hb1 + (size_t)NNODES * HID);  // [NNODES, HID] fp8
    bf16* Wt0 = (bf16*)(hf8 + (size_t)NNODES * HID);       // [128, 256]
    bf16* Wt1 = Wt0 + 128 * 256;                           // [128, 128]
    bf16* Wt2 = Wt1 + 128 * 128;                           // [64, 128]

    const int prepN = 128 * 256 + 128 * 128 + 64 * 128;
    prep_w<<<(prepN + 255) / 256, 256, 0, stream>>>(W0, W1, W2, Wt0, Wt1, Wt2);

    const int gGemm = (NNODES + 127) / 128;

    // layer 0
    gemm_nodes<NFEAT, false><<<gGemm, 256, 0, stream>>>(x, Wt0, b0, hb0, hf8, NNODES);
    agg_relu_fp8<<<NNODES / 4, 256, 0, stream>>>(hb0, hf8, hb1, ends, degree, att);
    // layer 1
    gemm_nodes<HID, true><<<gGemm, 256, 0, stream>>>(hb1, Wt1, b1, hb0, hf8, NNODES);
    agg_relu_fp8<<<NNODES / 4, 256, 0, stream>>>(
        hb0, hf8, hb1, ends + (size_t)KHOP * NNODES * RWSAMP, degree, att + KP1);
    // head
    head_mfma<<<gGemm, 256, 0, stream>>>(hb1, Wt2, b2, out, NNODES);
}

// Round 6
// 351.258 us; speedup vs baseline: 2.9496x; 1.0436x over previous
//
#include <hip/hip_runtime.h>
#include <math.h>

#define NNODES 100000
#define NFEAT  256
#define HID    128
#define NCLS   40
#define KHOP   4
#define RWSAMP 10
#define KP1    5

typedef __bf16 bf16;
typedef __attribute__((ext_vector_type(8)))  __bf16 bf16x8;
typedef __attribute__((ext_vector_type(2)))  float  f32x2;
typedef __attribute__((ext_vector_type(16))) float  f32x16;

// ---------------------------------------------------------------------------
// Prep: transpose+convert weights to bf16 [n][k] layout.
// ---------------------------------------------------------------------------
__global__ __launch_bounds__(256) void prep_w(
    const float* __restrict__ W0, const float* __restrict__ W1,
    const float* __restrict__ W2,
    bf16* __restrict__ Wt0, bf16* __restrict__ Wt1, bf16* __restrict__ Wt2)
{
    int tid = blockIdx.x * 256 + threadIdx.x;
    if (tid < 128 * 256) {
        int n = tid >> 8, k = tid & 255;
        Wt0[tid] = (bf16)W0[k * 128 + n];
    } else if (tid < 128 * 256 + 128 * 128) {
        int i = tid - 128 * 256;
        int n = i >> 7, k = i & 127;
        Wt1[i] = (bf16)W1[k * 128 + n];
    } else if (tid < 128 * 256 + 128 * 128 + 64 * 128) {
        int i = tid - (128 * 256 + 128 * 128);
        int n = i >> 7, k = i & 127;
        Wt2[i] = (n < NCLS) ? (bf16)W2[k * NCLS + n] : (bf16)0.0f;
    }
}

// ---------------------------------------------------------------------------
// GEMM: MFMA 32x32x16 bf16; output ONLY a row-major fp8-e4m3 table
// (via LDS 4x4 byte-transpose -> coalesced dword stores).
// Block 256 = 4 waves; M-tile 128; W streamed in BK=128 chunks; A staged
// per-wave (private LDS region, no cross-wave barrier).
// ---------------------------------------------------------------------------
template<int K, bool A_BF16>
__global__ __launch_bounds__(256) void gemm_nodes(
    const void* __restrict__ Av, const bf16* __restrict__ Wt,
    const float* __restrict__ bias, unsigned char* __restrict__ F8, int M)
{
    constexpr int BK  = 128;
    constexpr int LDB = BK + 4;                 // 132 elems = 264 B
    __shared__ bf16 Bs[128 * LDB];              // W chunk [n][k]
    __shared__ bf16 As[4][32 * LDB];            // per-wave A chunk [r][k]

    const int tid  = threadIdx.x;
    const int wv   = tid >> 6;
    const int lane = tid & 63;
    const int l31  = lane & 31;
    const int lhi  = lane >> 5;
    const int blockRow = blockIdx.x * 128;
    const int rowBase  = blockRow + wv * 32;

    const bf16*  Ab = (const bf16*)Av;
    const float* Af = (const float*)Av;

    f32x16 acc[4];
#pragma unroll
    for (int t = 0; t < 4; ++t)
#pragma unroll
        for (int r = 0; r < 16; ++r) acc[t][r] = 0.0f;

    for (int k0 = 0; k0 < K; k0 += BK) {
        if (k0) __syncthreads();
        // ---- stage W chunk ----
#pragma unroll 4
        for (int l = 0; l < 8; ++l) {
            int c   = tid + l * 256;
            int row = c >> 4;
            int kc  = (c & 15) * 8;
            uint4 v = *(const uint4*)(Wt + (size_t)row * K + k0 + kc);
            *(uint2*)&Bs[row * LDB + kc]     = make_uint2(v.x, v.y);
            *(uint2*)&Bs[row * LDB + kc + 4] = make_uint2(v.z, v.w);
        }
        __syncthreads();

        // ---- stage A per-wave (private region, no cross-wave barrier) ----
        if (A_BF16) {
#pragma unroll 4
            for (int l = 0; l < 8; ++l) {
                int c  = lane + l * 64;
                int r  = c >> 4;
                int kc = (c & 15) * 8;
                int gr = min(rowBase + r, M - 1);
                uint4 v = *(const uint4*)(Ab + (size_t)gr * K + k0 + kc);
                *(uint2*)&As[wv][r * LDB + kc]     = make_uint2(v.x, v.y);
                *(uint2*)&As[wv][r * LDB + kc + 4] = make_uint2(v.z, v.w);
            }
        } else {
#pragma unroll 4
            for (int l = 0; l < 16; ++l) {
                int c  = lane + l * 64;
                int r  = c >> 5;
                int kc = (c & 31) * 4;
                int gr = min(rowBase + r, M - 1);
                float4 v = *(const float4*)(Af + (size_t)gr * K + k0 + kc);
                union { bf16 h[4]; uint2 u; } t4;
                t4.h[0] = (bf16)v.x; t4.h[1] = (bf16)v.y;
                t4.h[2] = (bf16)v.z; t4.h[3] = (bf16)v.w;
                *(uint2*)&As[wv][r * LDB + kc] = t4.u;
            }
        }

        // ---- compute ----
#pragma unroll
        for (int ks = 0; ks < BK / 16; ++ks) {
            const int ko = ks * 16 + lhi * 8;
            union { uint2 u2[2]; bf16x8 v; } ua, ub;
            ua.u2[0] = *(const uint2*)&As[wv][l31 * LDB + ko];
            ua.u2[1] = *(const uint2*)&As[wv][l31 * LDB + ko + 4];
            bf16x8 a = ua.v;
#pragma unroll
            for (int t = 0; t < 4; ++t) {
                ub.u2[0] = *(const uint2*)&Bs[(t * 32 + l31) * LDB + ko];
                ub.u2[1] = *(const uint2*)&Bs[(t * 32 + l31) * LDB + ko + 4];
                acc[t] = __builtin_amdgcn_mfma_f32_32x32x16_bf16(a, ub.v, acc[t], 0, 0, 0);
            }
        }
    }

    __syncthreads();                // all waves done reading Bs before overlay
    unsigned* ldsq = (unsigned*)Bs; // [32 rowquads][128 cols] dwords (16 KB)

    // epilogue: fp8 pack (4 rows/dword) into LDS
#pragma unroll
    for (int t = 0; t < 4; ++t) {
        int col = t * 32 + l31;
        float bc = bias[col];
#pragma unroll
        for (int G = 0; G < 4; ++G) {
            float v0 = acc[t][4 * G + 0] + bc;
            float v1 = acc[t][4 * G + 1] + bc;
            float v2 = acc[t][4 * G + 2] + bc;
            float v3 = acc[t][4 * G + 3] + bc;
            int p = __builtin_amdgcn_cvt_pk_fp8_f32(v0, v1, 0, false);
            p = __builtin_amdgcn_cvt_pk_fp8_f32(v2, v3, p, true);
            ldsq[(wv * 8 + 2 * G + lhi) * 128 + col] = (unsigned)p;
        }
    }
    __syncthreads();

    // readout: 4x4 byte-transpose via v_perm, coalesced dword stores
    {
        const int j  = tid & 31;
        const int Q0 = (tid >> 5) * 4;
#pragma unroll
        for (int qq = 0; qq < 4; ++qq) {
            int Q = Q0 + qq;
            uint4 d = *(const uint4*)&ldsq[Q * 128 + 4 * j];
            int growb = blockRow + 4 * Q;
#pragma unroll
            for (int i = 0; i < 4; ++i) {
                unsigned sel = ((unsigned)(4 + i) << 8) | (unsigned)i;
                unsigned lo = __builtin_amdgcn_perm(d.y, d.x, sel);
                unsigned hi = __builtin_amdgcn_perm(d.w, d.z, sel);
                unsigned o  = __builtin_amdgcn_perm(hi, lo, 0x05040100u);
                if (growb + i < M)
                    *(unsigned*)(F8 + (size_t)(growb + i) * 128 + 4 * j) = o;
            }
        }
    }
}

// ---------------------------------------------------------------------------
// Aggregation + ReLU, all-fp8 reads, packed-f32 math. One wave per node.
// Lane-quarter q handles walks j=4t+q; lane owns 8 feats (dwordx2 per gather).
// Self-term also from the fp8 table. v_pk_fma via __builtin_elementwise_fma.
// ---------------------------------------------------------------------------
__global__ __launch_bounds__(256) void agg_relu_fp8(
    const unsigned char* __restrict__ hf8, bf16* __restrict__ hout,
    const int* __restrict__ ends, const float* __restrict__ degree,
    const float* __restrict__ att)
{
    __shared__ int2 sew[4][40];    // (e<<7, w bits)

    const int wv   = threadIdx.x >> 6;
    const int lane = threadIdx.x & 63;
    const int n    = blockIdx.x * 4 + wv;

    if (lane < KHOP * RWSAMP) {
        int k = lane / RWSAMP, s = lane - k * RWSAMP;
        int e = ends[(size_t)k * (NNODES * RWSAMP) + (size_t)n * RWSAMP + s];
        float w = att[k + 1] * (1.0f / RWSAMP) * sqrtf(degree[n]) * rsqrtf(degree[e]);
        sew[wv][lane] = make_int2(e << 7, __float_as_int(w));
    }
    // wave-private LDS region: same-wave producer/consumer, no barrier

    const int q  = lane >> 4;
    const int c8 = (lane & 15) * 8;

    f32x2 a0 = {0.f, 0.f}, a1 = {0.f, 0.f}, a2 = {0.f, 0.f}, a3 = {0.f, 0.f};

#pragma unroll
    for (int t = 0; t < 10; ++t) {
        int2  ew   = sew[wv][4 * t + q];
        unsigned v = (unsigned)ew.x + (unsigned)c8;
        float wj   = __int_as_float(ew.y);
        f32x2 w2   = {wj, wj};
        uint2 g = *(const uint2*)(hf8 + v);
        a0 = __builtin_elementwise_fma(w2, __builtin_amdgcn_cvt_pk_f32_fp8((int)g.x, false), a0);
        a1 = __builtin_elementwise_fma(w2, __builtin_amdgcn_cvt_pk_f32_fp8((int)g.x, true),  a1);
        a2 = __builtin_elementwise_fma(w2, __builtin_amdgcn_cvt_pk_f32_fp8((int)g.y, false), a2);
        a3 = __builtin_elementwise_fma(w2, __builtin_amdgcn_cvt_pk_f32_fp8((int)g.y, true),  a3);
    }

    // combine quarters (xor 16, 32)
    a0.x += __shfl_xor(a0.x, 16, 64); a0.y += __shfl_xor(a0.y, 16, 64);
    a1.x += __shfl_xor(a1.x, 16, 64); a1.y += __shfl_xor(a1.y, 16, 64);
    a2.x += __shfl_xor(a2.x, 16, 64); a2.y += __shfl_xor(a2.y, 16, 64);
    a3.x += __shfl_xor(a3.x, 16, 64); a3.y += __shfl_xor(a3.y, 16, 64);
    a0.x += __shfl_xor(a0.x, 32, 64); a0.y += __shfl_xor(a0.y, 32, 64);
    a1.x += __shfl_xor(a1.x, 32, 64); a1.y += __shfl_xor(a1.y, 32, 64);
    a2.x += __shfl_xor(a2.x, 32, 64); a2.y += __shfl_xor(a2.y, 32, 64);
    a3.x += __shfl_xor(a3.x, 32, 64); a3.y += __shfl_xor(a3.y, 32, 64);

    if (q == 0) {
        float att0 = att[0];
        f32x2 av = {att0, att0};
        unsigned vs = ((unsigned)n << 7) + (unsigned)c8;
        uint2 sv = *(const uint2*)(hf8 + vs);
        a0 = __builtin_elementwise_fma(av, __builtin_amdgcn_cvt_pk_f32_fp8((int)sv.x, false), a0);
        a1 = __builtin_elementwise_fma(av, __builtin_amdgcn_cvt_pk_f32_fp8((int)sv.x, true),  a1);
        a2 = __builtin_elementwise_fma(av, __builtin_amdgcn_cvt_pk_f32_fp8((int)sv.y, false), a2);
        a3 = __builtin_elementwise_fma(av, __builtin_amdgcn_cvt_pk_f32_fp8((int)sv.y, true),  a3);

        f32x2 z = {0.f, 0.f};
        a0 = __builtin_elementwise_max(a0, z);
        a1 = __builtin_elementwise_max(a1, z);
        a2 = __builtin_elementwise_max(a2, z);
        a3 = __builtin_elementwise_max(a3, z);

        union { bf16 h[8]; uint4 u; } st;
        st.h[0] = (bf16)a0.x; st.h[1] = (bf16)a0.y;
        st.h[2] = (bf16)a1.x; st.h[3] = (bf16)a1.y;
        st.h[4] = (bf16)a2.x; st.h[5] = (bf16)a2.y;
        st.h[6] = (bf16)a3.x; st.h[7] = (bf16)a3.y;
        *(uint4*)(hout + (size_t)n * HID + c8) = st.u;
    }
}

// ---------------------------------------------------------------------------
// Head: logits = h @ W2 + b2 via MFMA (N=64, cols>=40 zero), fused log_softmax.
// ---------------------------------------------------------------------------
__global__ __launch_bounds__(256) void head_mfma(
    const bf16* __restrict__ h, const bf16* __restrict__ Wt2,
    const float* __restrict__ b2, float* __restrict__ out, int M)
{
    constexpr int K = HID, LDB = K + 8;
    __shared__ bf16 Bs[64 * LDB];

    const int tid = threadIdx.x;
    constexpr int CPR = K / 8;
    for (int f = tid; f < 64 * CPR; f += 256) {
        int row = f / CPR;
        int kc  = (f % CPR) * 8;
        *(uint4*)&Bs[row * LDB + kc] = *(const uint4*)(Wt2 + (size_t)row * K + kc);
    }
    __syncthreads();

    const int wv   = tid >> 6;
    const int lane = tid & 63;
    const int l31  = lane & 31;
    const int lhi  = lane >> 5;
    const int blockRow = blockIdx.x * 128;
    const int arow = min(blockRow + wv * 32 + l31, M - 1);

    f32x16 acc[2];
#pragma unroll
    for (int t = 0; t < 2; ++t)
#pragma unroll
        for (int r = 0; r < 16; ++r) acc[t][r] = 0.0f;

#pragma unroll
    for (int ks = 0; ks < K / 16; ++ks) {
        bf16x8 a = *(const bf16x8*)(h + (size_t)arow * K + ks * 16 + lhi * 8);
#pragma unroll
        for (int t = 0; t < 2; ++t) {
            bf16x8 b = *(const bf16x8*)&Bs[(t * 32 + l31) * LDB + ks * 16 + lhi * 8];
            acc[t] = __builtin_amdgcn_mfma_f32_32x32x16_bf16(a, b, acc[t], 0, 0, 0);
        }
    }

    const float bc0 = b2[l31];
    const float bc1 = (l31 < 8) ? b2[32 + l31] : 0.0f;

#pragma unroll
    for (int r = 0; r < 16; ++r) {
        float v0 = acc[0][r] + bc0;
        float v1 = (l31 < 8) ? (acc[1][r] + bc1) : -INFINITY;

        float m = fmaxf(v0, v1);
#pragma unroll
        for (int off = 16; off > 0; off >>= 1)
            m = fmaxf(m, __shfl_xor(m, off, 64));

        float s = __expf(v0 - m) + ((l31 < 8) ? __expf(v1 - m) : 0.0f);
#pragma unroll
        for (int off = 16; off > 0; off >>= 1)
            s += __shfl_xor(s, off, 64);

        float ls = __logf(s);
        int grow = blockRow + wv * 32 + (r & 3) + 8 * (r >> 2) + 4 * lhi;
        if (grow < M) {
            out[(size_t)grow * NCLS + l31] = v0 - m - ls;
            if (l31 < 8)
                out[(size_t)grow * NCLS + 32 + l31] = v1 - m - ls;
        }
    }
}

extern "C" void kernel_launch(void* const* d_in, const int* in_sizes, int n_in,
                              void* d_out, int out_size, void* d_ws, size_t ws_size,
                              hipStream_t stream)
{
    const float* x      = (const float*)d_in[0];
    const float* degree = (const float*)d_in[1];
    const int*   ends   = (const int*)  d_in[2];
    const float* att    = (const float*)d_in[3];
    const float* W0     = (const float*)d_in[4];
    const float* b0     = (const float*)d_in[5];
    const float* W1     = (const float*)d_in[6];
    const float* b1     = (const float*)d_in[7];
    const float* W2     = (const float*)d_in[8];
    const float* b2     = (const float*)d_in[9];
    float* out = (float*)d_out;

    bf16* hb0 = (bf16*)d_ws;                               // [NNODES, HID] bf16
    bf16* hb1 = hb0 + (size_t)NNODES * HID;                // [NNODES, HID] bf16
    unsigned char* hf8 = (unsigned char*)(hb1 + (size_t)NNODES * HID);  // [NNODES, HID] fp8
    bf16* Wt0 = (bf16*)(hf8 + (size_t)NNODES * HID);       // [128, 256]
    bf16* Wt1 = Wt0 + 128 * 256;                           // [128, 128]
    bf16* Wt2 = Wt1 + 128 * 128;                           // [64, 128]

    const int prepN = 128 * 256 + 128 * 128 + 64 * 128;
    prep_w<<<(prepN + 255) / 256, 256, 0, stream>>>(W0, W1, W2, Wt0, Wt1, Wt2);

    const int gGemm = (NNODES + 127) / 128;

    // layer 0
    gemm_nodes<NFEAT, false><<<gGemm, 256, 0, stream>>>(x, Wt0, b0, hf8, NNODES);
    agg_relu_fp8<<<NNODES / 4, 256, 0, stream>>>(hf8, hb1, ends, degree, att);
    // layer 1
    gemm_nodes<HID, true><<<gGemm, 256, 0, stream>>>(hb1, Wt1, b1, hf8, NNODES);
    agg_relu_fp8<<<NNODES / 4, 256, 0, stream>>>(
        hf8, hb0, ends + (size_t)KHOP * NNODES * RWSAMP, degree, att + KP1);
    // head
    head_mfma<<<gGemm, 256, 0, stream>>>(hb0, Wt2, b2, out, NNODES);
}